// Round 17
// baseline (147.763 us; speedup 1.0000x reference)
//
#include <hip/hip_runtime.h>
#include <math.h>

#define N_NODES 80000
#define N_EDGES 1280000
#define D_NODE  128
#define D_EDGE  32
#define D_HID   64
#define NEG_SLOPE 0.2f
#define NB 313              // buckets of 256 target nodes
#define CAP 4608            // slab capacity per bucket (mean 4096 + 8 sigma)
#define BCNT_STRIDE 16      // one counter per 64B line
#define EB_CHUNK 2048
#define EB_NBLK 625         // edge-role blocks (= chunks, exact)
#define ND_NBLK 1250        // node-role blocks
#define ND_TILES 2500       // 32-node tiles

__device__ inline float waveReduceSum(float v) {
    #pragma unroll
    for (int o = 32; o > 0; o >>= 1) v += __shfl_xor(v, o);
    return v;
}
__device__ inline unsigned short f2bf(float f) {   // round-to-nearest-even bf16
    unsigned u = __float_as_uint(f);
    return (unsigned short)((u + 0x7FFF + ((u >> 16) & 1)) >> 16);
}
__device__ inline float bf2f(unsigned short v) {
    return __uint_as_float(((unsigned)v) << 16);
}

// Heterogeneous fused kernel: blocks [0,625) = edge score+bin (no s2 — deferred
// to accum); blocks [625,1875) = node transform. Roles are independent (disjoint
// outputs), so they overlap on the machine: edge is latency/memory-bound (3%
// VALU), node is VALU/LDS-bound (4% HBM) — complementary pipes. Edge blocks are
// dispatched first to occupy CUs for the long pole.
__global__ __launch_bounds__(512) void fused_kernel(
        const float* __restrict__ nf, const float* __restrict__ ef,
        const int* __restrict__ eidx,
        const float* __restrict__ w_w, const float* __restrict__ w_b,
        const float* __restrict__ ew_w, const float* __restrict__ ew_b,
        const float* __restrict__ a_w, const float* __restrict__ a_b,
        unsigned short* __restrict__ hb, float* __restrict__ s1, float* __restrict__ s2,
        int* __restrict__ bcnt, int2* __restrict__ binned) {
    __shared__ __align__(16) char smem[49152];   // 48 KB union
    int tid = threadIdx.x;

    if (blockIdx.x < EB_NBLK) {
        // ================= EDGE ROLE (R16 structure, s2 removed) =================
        float* cs      = (float*)smem;                 // [32]
        float* besp    = (float*)(smem + 128);
        int*   hist    = (int*)(smem + 256);           // [313]
        int*   gbase   = (int*)(smem + 1536);          // [313]
        int*   rank    = (int*)(smem + 2816);          // [313]
        int*   scanbuf = (int*)(smem + 4096);          // [512]
        float* sq      = (float*)(smem + 6144);        // [2048]
        int2*  sval    = (int2*)(smem + 14336);        // [2048]
        int*   sdst    = (int*)(smem + 30720);         // [2048]
        if (tid < D_EDGE) {
            float s = 0.f;
            #pragma unroll
            for (int d = 0; d < D_HID; ++d) s += ew_w[tid * D_HID + d] * a_w[2 * D_HID + d];
            cs[tid] = s;
        } else if (tid == D_EDGE) {
            float s = 0.f;
            #pragma unroll
            for (int d = 0; d < D_HID; ++d) s += ew_b[d] * a_w[2 * D_HID + d];
            *besp = s + a_b[0];
        }
        for (int i = tid; i < NB; i += 512) { hist[i] = 0; rank[i] = 0; }
        __syncthreads();
        float bes = *besp;
        int e0 = blockIdx.x * EB_CHUNK;                // one chunk per block
        // ---- Phase A: coalesced index loads (registers) + hist ----
        int RT[4], RN[4];
        #pragma unroll
        for (int k = 0; k < 4; ++k) {
            int idx = k * 512 + tid;
            int e = e0 + idx;
            RT[k] = eidx[e];
            RN[k] = eidx[N_EDGES + e];
            atomicAdd(&hist[RT[k] >> 8], 1);
        }
        // ---- Phase B: ef stream dot via 4-lane quads ----
        int qd = tid >> 2, j = tid & 3;
        const float4 c1 = *(const float4*)&cs[j * 4];
        const float4 c2 = *(const float4*)&cs[16 + j * 4];
        const float4* f4 = (const float4*)ef;
        #pragma unroll 2
        for (int rr = 0; rr < EB_CHUNK / 128; ++rr) {
            int idx = rr * 128 + qd;
            int e = e0 + idx;
            float4 fa = f4[(size_t)e * 8 + j];
            float4 fb = f4[(size_t)e * 8 + 4 + j];
            float p = fa.x * c1.x + fa.y * c1.y + fa.z * c1.z + fa.w * c1.w
                    + fb.x * c2.x + fb.y * c2.y + fb.z * c2.z + fb.w * c2.w;
            p += __shfl_xor(p, 1);
            p += __shfl_xor(p, 2);
            if (j == 0) sq[idx] = p + bes;             // q = ef.c + bes (no s2)
        }
        __syncthreads();
        // ---- Phase C: reserve global ranges + local scan of hist ----
        for (int i = tid; i < NB; i += 512) {
            int cc = hist[i];
            if (cc) gbase[i] = i * CAP + atomicAdd(&bcnt[i * BCNT_STRIDE], cc);
        }
        scanbuf[tid] = (tid < NB) ? hist[tid] : 0;
        __syncthreads();
        for (int ofs = 1; ofs < 512; ofs <<= 1) {
            int t = (tid >= (unsigned)ofs) ? scanbuf[tid - ofs] : 0;
            __syncthreads();
            scanbuf[tid] += t;
            __syncthreads();
        }
        // ---- Phase D1: scatter into LDS slab (slab order) ----
        #pragma unroll
        for (int k = 0; k < 4; ++k) {
            int idx = k * 512 + tid;
            int tg = RT[k];
            int b  = tg >> 8;
            int r  = atomicAdd(&rank[b], 1);
            int slot = scanbuf[b] - hist[b] + r;
            sval[slot] = make_int2(((tg & 255) << 17) | RN[k],
                                   __float_as_int(sq[idx]));
            sdst[slot] = gbase[b] + r;
        }
        __syncthreads();
        // ---- Phase D2: linear sweep, ascending-address coalesced stores ----
        #pragma unroll
        for (int k = 0; k < 4; ++k) {
            int i = k * 512 + tid;
            binned[sdst[i]] = sval[i];
        }
    } else {
        // ================= NODE ROLE (32-node tiles, 4 nodes/wave) =================
        float* Ws = (float*)smem;                      // [64*128] swizzled W^T, 32 KB
        float* Xs = (float*)(smem + 32768);            // [32][128], 16 KB
        for (int i = tid; i < D_NODE * D_HID; i += 512) {
            int k = i >> 6, d = i & 63;                // w_w[k][d]
            Ws[d * D_NODE + (((k >> 2) ^ (d & 7)) << 2) + (k & 3)] = w_w[i];
        }
        int lane = tid & 63;
        int wv   = tid >> 6;                           // 0..7
        float wb = w_b[lane];
        float a1 = a_w[lane];
        float a2 = a_w[D_HID + lane];
        const float* wrow = &Ws[lane * D_NODE];
        for (int tile = (int)blockIdx.x - EB_NBLK; tile < ND_TILES; tile += ND_NBLK) {
            int n0 = tile * 32;
            __syncthreads();
            {   // stage 32 rows = 1024 float4, 2 per thread, coalesced
                const float4* src = (const float4*)(nf + (size_t)n0 * D_NODE);
                float4* dst = (float4*)Xs;
                dst[tid]       = src[tid];
                dst[tid + 512] = src[tid + 512];
            }
            __syncthreads();
            float acc[4] = {0.f, 0.f, 0.f, 0.f};
            const float* xs = &Xs[(size_t)wv * 4 * D_NODE];
            #pragma unroll 4
            for (int k4 = 0; k4 < 32; ++k4) {
                float4 w = *(const float4*)&wrow[(k4 ^ (lane & 7)) << 2];
                #pragma unroll
                for (int n = 0; n < 4; ++n) {
                    float4 x = *(const float4*)&xs[n * D_NODE + (k4 << 2)];
                    acc[n] += w.x * x.x + w.y * x.y + w.z * x.z + w.w * x.w;
                }
            }
            #pragma unroll
            for (int n = 0; n < 4; ++n) {
                int node = n0 + wv * 4 + n;
                float hv = acc[n] + wb;
                hb[(size_t)node * D_HID + lane] = f2bf(hv);
                float r1 = waveReduceSum(hv * a1);
                float r2 = waveReduceSum(hv * a2);
                if (lane == 0) { s1[node] = r1; s2[node] = r2; }
            }
        }
    }
}

// Merged CSR + accum (R15/R16 structure) with the deferred s2[nbr] gather:
// s = s1[node] + q + s2[nbr]; leaky; exp; weighted bf16 h-row gather; elu.
__global__ __launch_bounds__(1024) void bucket_accum_kernel(
        const int* __restrict__ bcnt, const int2* __restrict__ binned,
        const float* __restrict__ s1, const float* __restrict__ s2v,
        const unsigned short* __restrict__ hb, float* __restrict__ out) {
    __shared__ int nhist[256], buf[256], sbase[256], ncur[256];
    __shared__ int2 slab[CAP];        // 36 KB
    int tid = threadIdx.x;
    int b = blockIdx.x;
    int in0 = b * CAP;
    int cnt = bcnt[b * BCNT_STRIDE];
    if (tid < 256) nhist[tid] = 0;
    __syncthreads();
    for (int i = tid; i < cnt; i += 1024)
        atomicAdd(&nhist[binned[in0 + i].x >> 17], 1);
    __syncthreads();
    if (tid < 256) buf[tid] = nhist[tid];
    __syncthreads();
    for (int ofs = 1; ofs < 256; ofs <<= 1) {
        int t = 0;
        if (tid < 256 && tid >= ofs) t = buf[tid - ofs];
        __syncthreads();
        if (tid < 256) buf[tid] += t;
        __syncthreads();
    }
    if (tid < 256) {
        int excl = buf[tid] - nhist[tid];
        sbase[tid] = excl;
        ncur[tid]  = excl;
    }
    __syncthreads();
    for (int i = tid; i < cnt; i += 1024) {
        int2 p = binned[in0 + i];
        int r = atomicAdd(&ncur[p.x >> 17], 1);
        slab[r] = make_int2(p.x & 0x1FFFF, p.y);   // {nbr, q bits}
    }
    __syncthreads();
    int grp = tid >> 4;               // 0..63
    int li  = tid & 15;
    int wl  = ((tid & 63) >> 4) << 4; // group base lane within wave
    for (int nl = grp; nl < 256; nl += 64) {
        int node = b * 256 + nl;
        if (node >= N_NODES) break;
        int base = sbase[nl];
        int cn   = nhist[nl];
        float s1i = s1[node];
        float ax = 0.f, ay = 0.f, az = 0.f, aw = 0.f, sumex = 0.f;
        for (int c0 = 0; c0 < cn; c0 += 16) {
            int i = c0 + li;
            int nc = min(16, cn - c0);
            float exv = 0.f; int nbv = 0;
            if (i < cn) {
                int2 p = slab[base + i];
                nbv = p.x;
                float s = s1i + __int_as_float(p.y) + s2v[nbv];  // deferred s2
                s = (s > 0.f) ? s : NEG_SLOPE * s;
                exv = __expf(s);      // un-normalized (exp safe in f32)
            }
            sumex += exv;
            for (int jj = 0; jj < nc; ++jj) {
                float w  = __shfl(exv, wl + jj);
                int   nb = __shfl(nbv, wl + jj);
                uint2 v = *(const uint2*)&hb[(size_t)nb * D_HID + li * 4];
                ax += w * bf2f((unsigned short)(v.x & 0xFFFF));
                ay += w * bf2f((unsigned short)(v.x >> 16));
                az += w * bf2f((unsigned short)(v.y & 0xFFFF));
                aw += w * bf2f((unsigned short)(v.y >> 16));
            }
        }
        #pragma unroll
        for (int o = 8; o > 0; o >>= 1) sumex += __shfl_xor(sumex, o);
        float4 o4;
        if (cn == 0) {
            o4 = make_float4(0.f, 0.f, 0.f, 0.f);
        } else {
            o4.x = ax / sumex; o4.y = ay / sumex; o4.z = az / sumex; o4.w = aw / sumex;
            o4.x = (o4.x > 0.f) ? o4.x : (__expf(o4.x) - 1.f);
            o4.y = (o4.y > 0.f) ? o4.y : (__expf(o4.y) - 1.f);
            o4.z = (o4.z > 0.f) ? o4.z : (__expf(o4.z) - 1.f);
            o4.w = (o4.w > 0.f) ? o4.w : (__expf(o4.w) - 1.f);
        }
        ((float4*)out)[(size_t)node * 16 + li] = o4;
    }
}

extern "C" void kernel_launch(void* const* d_in, const int* in_sizes, int n_in,
                              void* d_out, int out_size, void* d_ws, size_t ws_size,
                              hipStream_t stream) {
    const float* nf   = (const float*)d_in[0];
    const float* ef   = (const float*)d_in[1];
    const int*   eidx = (const int*)d_in[2];
    const float* w_w  = (const float*)d_in[3];
    const float* w_b  = (const float*)d_in[4];
    const float* ew_w = (const float*)d_in[5];
    const float* ew_b = (const float*)d_in[6];
    const float* a_w  = (const float*)d_in[7];
    const float* a_b  = (const float*)d_in[8];
    float* out = (float*)d_out;

    char* ws = (char*)d_ws;
    size_t o = 0;
    auto alloc = [&](size_t bytes) -> void* {
        void* p = ws + o;
        o = (o + bytes + 255) & ~(size_t)255;
        return p;
    };
    unsigned short* hb  = (unsigned short*)alloc((size_t)N_NODES * D_HID * 2);
    float* s1       = (float*)alloc((size_t)N_NODES * 4);
    float* s2       = (float*)alloc((size_t)N_NODES * 4);
    int*   bcnt     = (int*)alloc((size_t)NB * BCNT_STRIDE * 4);
    int2*  binned   = (int2*)alloc((size_t)NB * CAP * 8);

    hipMemsetAsync(bcnt, 0, (size_t)NB * BCNT_STRIDE * 4, stream);

    fused_kernel<<<EB_NBLK + ND_NBLK, 512, 0, stream>>>(
        nf, ef, eidx, w_w, w_b, ew_w, ew_b, a_w, a_b, hb, s1, s2, bcnt, binned);
    bucket_accum_kernel<<<NB, 1024, 0, stream>>>(bcnt, binned, s1, s2, hb, out);
}